// Round 24
// baseline (776.796 us; speedup 1.0000x reference)
//
#include <hip/hip_runtime.h>

// Problem constants (match reference setup_inputs)
constexpr int NVn = 200000;   // var nodes, 9 feats in
constexpr int NCn = 100000;   // cstr nodes, 1 feat in
constexpr int NEn = 1000000;  // edges
constexpr int NBb = 32;       // graphs
#define EPSf 1e-5f

typedef unsigned short u16;
typedef __attribute__((ext_vector_type(8))) short s8v;   // 8 bf16 (4 VGPRs)
typedef __attribute__((ext_vector_type(4))) float f4v;   // 4 f32 acc

// f32 -> bf16 bits, round-to-nearest-even
static __device__ __forceinline__ u16 f2b(float f) {
    union { float f; unsigned u; } x; x.f = f;
    return (u16)((x.u + 0x7FFFu + ((x.u >> 16) & 1u)) >> 16);
}
static __device__ __forceinline__ float b2f(u16 u) {
    union { unsigned u; float f; } x; x.u = ((unsigned)u) << 16; return x.f;
}

// store folded weight W[kg][h] (kg in 0..127, h in 0..63) into MFMA B-fragment order:
// fragment (ks=kg>>5, ct=h>>4), lane = ((kg>>3)&3)<<4 | (h&15), elem j = kg&7
static __device__ __forceinline__ void frag_store(u16* B, int kg, int h, float w) {
    int ks = kg >> 5, g = (kg >> 3) & 3, j = kg & 7, ct = h >> 4;
    int lane = (g << 4) | (h & 15);
    B[((((ks << 2) | ct) << 6) | lane) * 8 + j] = f2b(w);
}

// ---------------- degree count (2 edges/thread, int2 loads) ----------------
__global__ __launch_bounds__(256) void k_count_deg(const int* __restrict__ src, const int* __restrict__ dst,
                            int* __restrict__ degv, int* __restrict__ degc) {
    int i = blockIdx.x * blockDim.x + threadIdx.x;
    for (int e2 = i; e2 < NEn / 2; e2 += gridDim.x * blockDim.x) {
        int2 s = ((const int2*)src)[e2];
        int2 d = ((const int2*)dst)[e2];
        atomicAdd(&degv[d.x], 1);
        atomicAdd(&degv[d.y], 1);
        atomicAdd(&degc[s.x], 1);
        atomicAdd(&degc[s.y], 1);
    }
}

// ---------------- exclusive scan (3 kernels, 1024 elems/block) ----------------
__global__ __launch_bounds__(256) void k_scan_block(const int* __restrict__ deg, int n, int* __restrict__ bsum) {
    __shared__ int s[256];
    int base = blockIdx.x * 1024;
    int t = threadIdx.x;
    int v = 0;
#pragma unroll
    for (int j = 0; j < 4; j++) { int idx = base + t * 4 + j; if (idx < n) v += deg[idx]; }
    s[t] = v; __syncthreads();
    for (int o = 128; o > 0; o >>= 1) { if (t < o) s[t] += s[t + o]; __syncthreads(); }
    if (t == 0) bsum[blockIdx.x] = s[0];
}

__global__ __launch_bounds__(1024) void k_scan_tops(int* bsum, int nb) {
    __shared__ int s[1024];
    int t = threadIdx.x;
    int v = (t < nb) ? bsum[t] : 0;
    s[t] = v; __syncthreads();
    for (int o = 1; o < 1024; o <<= 1) {
        int x = (t >= o) ? s[t - o] : 0; __syncthreads();
        s[t] += x; __syncthreads();
    }
    if (t < nb) bsum[t] = s[t] - v;  // exclusive
}

__global__ __launch_bounds__(256) void k_scan_final(const int* __restrict__ deg, int n, const int* __restrict__ bsum,
                             int* __restrict__ off, int* __restrict__ cur) {
    __shared__ int s[256];
    int base = blockIdx.x * 1024, t = threadIdx.x;
    int d[4], loc[4], sum = 0;
#pragma unroll
    for (int j = 0; j < 4; j++) {
        int idx = base + t * 4 + j;
        d[j] = (idx < n) ? deg[idx] : 0;
        loc[j] = sum; sum += d[j];
    }
    s[t] = sum; __syncthreads();
    int v = sum;
    for (int o = 1; o < 256; o <<= 1) {
        int x = (t >= o) ? s[t - o] : 0; __syncthreads();
        s[t] += x; __syncthreads();
    }
    int texcl = s[t] - v + bsum[blockIdx.x];
#pragma unroll
    for (int j = 0; j < 4; j++) {
        int idx = base + t * 4 + j;
        if (idx < n) {
            int o2 = texcl + loc[j];
            off[idx] = o2; cur[idx] = o2;
            if (idx == n - 1) off[n] = o2 + d[j];
        }
    }
}

// ---------------- CSR fill, BOTH directions in one pass ----------------
__global__ __launch_bounds__(256) void k_fill_both(const int* __restrict__ src, const int* __restrict__ dst,
                       const float* __restrict__ ew, const int* __restrict__ off,
                       int* __restrict__ cur, int2* __restrict__ erec) {
    for (int e = blockIdx.x * blockDim.x + threadIdx.x; e < NEn; e += gridDim.x * blockDim.x) {
        int s = src[e], d = dst[e];
        float a = ew[e];
        int degv = off[d + 1] - off[d];
        int p = atomicAdd(&cur[d], 1);
        erec[p] = make_int2(s, __float_as_int(a * (1.0f / (float)degv)));
        int kc = NVn + s;
        int degc = off[kc + 1] - off[kc];
        int p2 = atomicAdd(&cur[kc], 1);
        erec[p2] = make_int2(d, __float_as_int(a * (1.0f / (float)degc)));
    }
}

// wsum[i] = sum of (ew/deg) over row
__global__ __launch_bounds__(256) void k_wsum_rec(const int* __restrict__ off, const int2* __restrict__ erec,
                       float* __restrict__ ws, int n) {
    for (int i = blockIdx.x * blockDim.x + threadIdx.x; i < n; i += gridDim.x * blockDim.x) {
        int s = off[i], e = off[i + 1]; float t = 0.f;
        for (int j = s; j < e; j++) t += __int_as_float(erec[j].y);
        ws[i] = t;
    }
}

// f32 input, small D: 1 row/thread, wave shuffle-reduce, 2D atomics/block
template <int D>
__global__ __launch_bounds__(256) void k_stats_small(const float* __restrict__ x, int n, float* __restrict__ acc) {
    float s[D], q[D];
#pragma unroll
    for (int k = 0; k < D; k++) { s[k] = 0.f; q[k] = 0.f; }
    for (int i = blockIdx.x * blockDim.x + threadIdx.x; i < n; i += gridDim.x * blockDim.x) {
#pragma unroll
        for (int k = 0; k < D; k++) { float v = x[(size_t)i * D + k]; s[k] += v; q[k] = fmaf(v, v, q[k]); }
    }
#pragma unroll
    for (int k = 0; k < D; k++) {
#pragma unroll
        for (int o = 32; o > 0; o >>= 1) {
            s[k] += __shfl_down(s[k], o);
            q[k] += __shfl_down(q[k], o);
        }
    }
    __shared__ float ls[4][2 * D];
    int lane = threadIdx.x & 63, wv = threadIdx.x >> 6;
    if (lane == 0) {
#pragma unroll
        for (int k = 0; k < D; k++) { ls[wv][k] = s[k]; ls[wv][D + k] = q[k]; }
    }
    __syncthreads();
    int t = threadIdx.x;
    if (t < 2 * D) atomicAdd(&acc[t], ls[0][t] + ls[1][t] + ls[2][t] + ls[3][t]);
}

// ---------------- fold BN into weights (2 param sets in one launch; block 0=A, 1=B) ------
struct FoldArgs {
    const float *Wrel, *brel, *Wroot, *gs, *bs, *accs, *gd, *bd, *accd;
    float invNs, invNd;
    int DSv, DDv;
    float *Wr_o, *Wt_o, *b0_o, *bw_o;
    u16* Bfrag;
};

__global__ __launch_bounds__(256) void k_fold2(FoldArgs A, FoldArgs B) {
    const FoldArgs F = blockIdx.x ? B : A;
    __shared__ float sa[128], sbe[128];
    __shared__ float rb0[4][64], rbw[4][64];
    int t = threadIdx.x;
    int total = F.DSv + F.DDv;
    for (int k = t; k < total; k += 256) {
        bool isrc = k < F.DSv;
        int kk = isrc ? k : k - F.DSv;
        const float* acc = isrc ? F.accs : F.accd;
        float invN = isrc ? F.invNs : F.invNd;
        int D = isrc ? F.DSv : F.DDv;
        float g = isrc ? F.gs[kk] : F.gd[kk];
        float b = isrc ? F.bs[kk] : F.bd[kk];
        float m = acc[kk] * invN;
        float var = acc[D + kk] * invN - m * m;
        float a = g * rsqrtf(var + EPSf);
        sa[k] = a; sbe[k] = b - m * a;
    }
    __syncthreads();
    int h = t & 63, q = t >> 6;
    float bw = 0.f, b0 = 0.f;
    for (int k = q; k < F.DSv; k += 4) {
        float wv = F.Wrel[k * 64 + h];
        float wf = sa[k] * wv;
        F.Wr_o[k * 64 + h] = wf;
        bw = fmaf(sbe[k], wv, bw);
        if (F.Bfrag) frag_store(F.Bfrag, k, h, wf);
    }
    for (int k = q; k < F.DDv; k += 4) {
        float wv = F.Wroot[k * 64 + h];
        float wf = sa[F.DSv + k] * wv;
        F.Wt_o[k * 64 + h] = wf;
        b0 = fmaf(sbe[F.DSv + k], wv, b0);
        if (F.Bfrag) frag_store(F.Bfrag, 64 + k, h, wf);
    }
    rb0[q][h] = b0; rbw[q][h] = bw;
    __syncthreads();
    if (q == 0) {
        F.b0_o[h] = F.brel[h] + rb0[0][h] + rb0[1][h] + rb0[2][h] + rb0[3][h];
        F.bw_o[h] = rbw[0][h] + rbw[1][h] + rbw[2][h] + rbw[3][h];
    }
}

// ---------------- MERGED layer 0 (v blocks then c blocks) --------
__global__ __launch_bounds__(256, 4) void k_layer0(
        const float* __restrict__ cf, const float* __restrict__ vf,
        const int* __restrict__ off_v, const int* __restrict__ off_c,
        const int2* __restrict__ erec,
        const float* __restrict__ wsum_v, const float* __restrict__ wsum_c,
        const float* __restrict__ Wr_v, const float* __restrict__ Wt_v,
        const float* __restrict__ b0_v, const float* __restrict__ bw_v,
        const float* __restrict__ Wr_c, const float* __restrict__ Wt_c,
        const float* __restrict__ b0_c, const float* __restrict__ bw_c,
        u16* __restrict__ outv, u16* __restrict__ outc,
        float* __restrict__ accv, float* __restrict__ accc, int nbv) {
    __shared__ float ls[4][128];
    int t = threadIdx.x, h = t & 63, wv = t >> 6;
    if ((int)blockIdx.x < nbv) {
        // ---- v-update: 4 rows/wave; 16-lane gather groups ----
        int wid = blockIdx.x * 4 + wv, nw = nbv * 4;
        int grp = h >> 4, sub = h & 15;
        float wr = Wr_v[h], bb = b0_v[h], wb = bw_v[h];
        float wt[9];
#pragma unroll
        for (int k = 0; k < 9; k++) wt[k] = Wt_v[k * 64 + h];
        float ssum = 0.f, sq = 0.f;
        for (int i0 = wid * 4; i0 < NVn; i0 += nw * 4) {
            int row = i0 + grp;
            bool ok = row < NVn;
            int s = ok ? off_v[row] : 0;
            int e = ok ? off_v[row + 1] : 0;
            float p = 0.f;
            for (int j = s + sub; j < e; j += 16) {
                int2 r = erec[j];
                p = fmaf(__int_as_float(r.y), cf[r.x], p);
            }
            p += __shfl_xor(p, 1); p += __shfl_xor(p, 2);
            p += __shfl_xor(p, 4); p += __shfl_xor(p, 8);
#pragma unroll
            for (int r = 0; r < 4; ++r) {
                int orow = i0 + r;
                if (orow >= NVn) break;
                float pr = __shfl(p, r * 16);
                float acc = fmaf(pr, wr, bb) + wsum_v[orow] * wb;
#pragma unroll
                for (int k = 0; k < 9; k++) acc = fmaf(vf[(size_t)orow * 9 + k], wt[k], acc);
                float v = fmaxf(acc, 0.f);
                outv[(size_t)orow * 64 + h] = f2b(v);
                ssum += v; sq = fmaf(v, v, sq);
            }
        }
        ls[wv][h] = ssum; ls[wv][64 + h] = sq;
        __syncthreads();
        if (t < 128) atomicAdd(&accv[t], ls[0][t] + ls[1][t] + ls[2][t] + ls[3][t]);
    } else {
        // ---- c-update: 2 rows/wave; 32-lane gather groups (9 feats) ----
        int blk = blockIdx.x - nbv;
        int nbc = gridDim.x - nbv;
        int wid = blk * 4 + wv, nw = nbc * 4;
        int grp = h >> 5, sub = h & 31;
        float wtt = Wt_c[h], bb = b0_c[h], wb = bw_c[h];
        float wr[9];
#pragma unroll
        for (int k = 0; k < 9; k++) wr[k] = Wr_c[k * 64 + h];
        float ssum = 0.f, sq = 0.f;
        for (int i0 = wid * 2; i0 < NCn; i0 += nw * 2) {
            int row = i0 + grp;
            bool ok = row < NCn;
            int s = ok ? off_c[row] : 0;
            int e = ok ? off_c[row + 1] : 0;
            float p[9];
#pragma unroll
            for (int k = 0; k < 9; k++) p[k] = 0.f;
            for (int j = s + sub; j < e; j += 32) {
                int2 r = erec[j];
                float w = __int_as_float(r.y);
#pragma unroll
                for (int k = 0; k < 9; k++) p[k] = fmaf(w, vf[(size_t)r.x * 9 + k], p[k]);
            }
#pragma unroll
            for (int k = 0; k < 9; k++) {
                p[k] += __shfl_xor(p[k], 1); p[k] += __shfl_xor(p[k], 2);
                p[k] += __shfl_xor(p[k], 4); p[k] += __shfl_xor(p[k], 8);
                p[k] += __shfl_xor(p[k], 16);
            }
#pragma unroll
            for (int r = 0; r < 2; ++r) {
                int orow = i0 + r;
                if (orow >= NCn) break;
                float acc = fmaf(cf[orow], wtt, bb) + wsum_c[orow] * wb;
#pragma unroll
                for (int k = 0; k < 9; k++) {
                    float pr = __shfl(p[k], r * 32);
                    acc = fmaf(pr, wr[k], acc);
                }
                float v = fmaxf(acc, 0.f);
                outc[(size_t)orow * 64 + h] = f2b(v);
                ssum += v; sq = fmaf(v, v, sq);
            }
        }
        ls[wv][h] = ssum; ls[wv][64 + h] = sq;
        __syncthreads();
        if (t < 128) atomicAdd(&accc[t], ls[0][t] + ls[1][t] + ls[2][t] + ls[3][t]);
    }
}

// ---------------- FUSED layer body: agg (gather) + MFMA GEMM + epilogue + stats ----
// Round-24: 8 groups x 8 lanes x ushort8 (16B/lane) -- one gather instruction now
// covers 8 edges (was 4 via 16x ushort4), halving VMEM + meta instruction count in
// the latency-bound phase 1. NB2 = 8-edge slots in fast path (v:1, c:2).
struct LArgs {
    const u16 *xs, *xr;
    const int* off;
    const float* wsum;
    const u16* Bfrag;
    const float *b0v, *bwv;
    u16* out;
    float* statacc;
    int n;
};

template <int NB2>
static __device__ __forceinline__ void layer_body(const LArgs& A, const int2* __restrict__ erec,
                                                  int blk, u16 (*lagg)[16][72], float (*lstat)[2][64]) {
    constexpr int RPB = 8 / NB2;   // rows per batch (8 VMEM instrs in flight)
    int t = threadIdx.x;
    int wv = t >> 6, l = t & 63;
    int lrow = l & 15, lkg = l >> 4;
    int base = blk * 64 + wv * 16;
    int n = A.n;
    // phase 1: aggregate (8 groups of 8 lanes; lane qi loads 16B of its edge's row)
    {
        int g = l >> 3, qi = l & 7;
        int offv = 0;
        if (l < 17) { int idx = base + l; offv = A.off[idx > n ? n : idx]; }
#pragma unroll
        for (int ob = 0; ob < 16 / RPB; ++ob) {
            int s_[RPB], e_[RPB];
            int cc[RPB][NB2];
            float ww[RPB][NB2];
#pragma unroll
            for (int rr = 0; rr < RPB; ++rr) {
                int r = ob * RPB + rr;
                int s = __shfl(offv, r);
                int e = __shfl(offv, r + 1);
                s_[rr] = s; e_[rr] = e;
#pragma unroll
                for (int b = 0; b < NB2; ++b) {
                    int d = e - s - 8 * b;
                    int idx = (d > 0) ? (s + 8 * b + (g < d ? g : 0)) : 0;
                    int2 rec = erec[idx];
                    cc[rr][b] = rec.x;
                    float wv2 = __int_as_float(rec.y);
                    if (g >= d) wv2 = 0.f;
                    ww[rr][b] = wv2;
                }
            }
            s8v ft[RPB][NB2];
#pragma unroll
            for (int rr = 0; rr < RPB; ++rr)
#pragma unroll
                for (int b = 0; b < NB2; ++b)
                    ft[rr][b] = *(const s8v*)(A.xs + (size_t)cc[rr][b] * 64 + qi * 8);
#pragma unroll
            for (int rr = 0; rr < RPB; ++rr) {
                float a0 = 0.f, a1 = 0.f, a2 = 0.f, a3 = 0.f;
                float a4 = 0.f, a5 = 0.f, a6 = 0.f, a7 = 0.f;
#pragma unroll
                for (int b = 0; b < NB2; ++b) {
                    float w = ww[rr][b];
                    a0 = fmaf(w, b2f((u16)ft[rr][b][0]), a0);
                    a1 = fmaf(w, b2f((u16)ft[rr][b][1]), a1);
                    a2 = fmaf(w, b2f((u16)ft[rr][b][2]), a2);
                    a3 = fmaf(w, b2f((u16)ft[rr][b][3]), a3);
                    a4 = fmaf(w, b2f((u16)ft[rr][b][4]), a4);
                    a5 = fmaf(w, b2f((u16)ft[rr][b][5]), a5);
                    a6 = fmaf(w, b2f((u16)ft[rr][b][6]), a6);
                    a7 = fmaf(w, b2f((u16)ft[rr][b][7]), a7);
                }
                for (int j = s_[rr] + 8 * NB2; j < e_[rr]; j += 8) {
                    int rem = e_[rr] - j;
                    int i2 = j + (g < rem ? g : 0);
                    int2 rec = erec[i2];
                    float w2 = __int_as_float(rec.y); if (g >= rem) w2 = 0.f;
                    s8v f2 = *(const s8v*)(A.xs + (size_t)rec.x * 64 + qi * 8);
                    a0 = fmaf(w2, b2f((u16)f2[0]), a0);
                    a1 = fmaf(w2, b2f((u16)f2[1]), a1);
                    a2 = fmaf(w2, b2f((u16)f2[2]), a2);
                    a3 = fmaf(w2, b2f((u16)f2[3]), a3);
                    a4 = fmaf(w2, b2f((u16)f2[4]), a4);
                    a5 = fmaf(w2, b2f((u16)f2[5]), a5);
                    a6 = fmaf(w2, b2f((u16)f2[6]), a6);
                    a7 = fmaf(w2, b2f((u16)f2[7]), a7);
                }
                a0 += __shfl_xor(a0, 8); a0 += __shfl_xor(a0, 16); a0 += __shfl_xor(a0, 32);
                a1 += __shfl_xor(a1, 8); a1 += __shfl_xor(a1, 16); a1 += __shfl_xor(a1, 32);
                a2 += __shfl_xor(a2, 8); a2 += __shfl_xor(a2, 16); a2 += __shfl_xor(a2, 32);
                a3 += __shfl_xor(a3, 8); a3 += __shfl_xor(a3, 16); a3 += __shfl_xor(a3, 32);
                a4 += __shfl_xor(a4, 8); a4 += __shfl_xor(a4, 16); a4 += __shfl_xor(a4, 32);
                a5 += __shfl_xor(a5, 8); a5 += __shfl_xor(a5, 16); a5 += __shfl_xor(a5, 32);
                a6 += __shfl_xor(a6, 8); a6 += __shfl_xor(a6, 16); a6 += __shfl_xor(a6, 32);
                a7 += __shfl_xor(a7, 8); a7 += __shfl_xor(a7, 16); a7 += __shfl_xor(a7, 32);
                if (g == 0) {
                    s8v o;
                    o[0] = (short)f2b(a0); o[1] = (short)f2b(a1);
                    o[2] = (short)f2b(a2); o[3] = (short)f2b(a3);
                    o[4] = (short)f2b(a4); o[5] = (short)f2b(a5);
                    o[6] = (short)f2b(a6); o[7] = (short)f2b(a7);
                    *(s8v*)&lagg[wv][ob * RPB + rr][qi * 8] = o;
                }
            }
        }
    }
    // phase 2: MFMA (per-wave LDS region: wave-synchronous, no barrier needed)
    const u16* Bl = A.Bfrag + l * 8;
    f4v acc0 = {0.f, 0.f, 0.f, 0.f};
    f4v acc1 = acc0, acc2 = acc0, acc3 = acc0;
#define LSTEP(ks, APTR)                                                       \
    {                                                                         \
        s8v a = *(const s8v*)(APTR);                                          \
        s8v f0 = *(const s8v*)(Bl + ((ks) * 4 + 0) * 512);                    \
        s8v f1 = *(const s8v*)(Bl + ((ks) * 4 + 1) * 512);                    \
        s8v f2 = *(const s8v*)(Bl + ((ks) * 4 + 2) * 512);                    \
        s8v f3 = *(const s8v*)(Bl + ((ks) * 4 + 3) * 512);                    \
        acc0 = __builtin_amdgcn_mfma_f32_16x16x32_bf16(a, f0, acc0, 0, 0, 0); \
        acc1 = __builtin_amdgcn_mfma_f32_16x16x32_bf16(a, f1, acc1, 0, 0, 0); \
        acc2 = __builtin_amdgcn_mfma_f32_16x16x32_bf16(a, f2, acc2, 0, 0, 0); \
        acc3 = __builtin_amdgcn_mfma_f32_16x16x32_bf16(a, f3, acc3, 0, 0, 0); \
    }
    LSTEP(0, &lagg[wv][lrow][lkg * 8])
    LSTEP(1, &lagg[wv][lrow][32 + lkg * 8])
    int arow = base + lrow; if (arow >= n) arow = 0;
    const u16* xp = A.xr + (size_t)arow * 64 + lkg * 8;
    LSTEP(2, xp)
    LSTEP(3, xp + 32)
#undef LSTEP
    // phase 3: epilogue + stats
    int orow = base + lkg * 4;
    bool ok0 = orow + 0 < n, ok1 = orow + 1 < n, ok2 = orow + 2 < n, ok3 = orow + 3 < n;
    float ws0 = ok0 ? A.wsum[orow + 0] : 0.f;
    float ws1 = ok1 ? A.wsum[orow + 1] : 0.f;
    float ws2 = ok2 ? A.wsum[orow + 2] : 0.f;
    float ws3 = ok3 ? A.wsum[orow + 3] : 0.f;
#define EPI(ACC, ct)                                                              \
    {                                                                             \
        int c = (ct) * 16 + lrow;                                                 \
        float bb = A.b0v[c], wb = A.bwv[c];                                       \
        float v0 = ok0 ? fmaxf(ACC[0] + bb + ws0 * wb, 0.f) : 0.f;                \
        float v1 = ok1 ? fmaxf(ACC[1] + bb + ws1 * wb, 0.f) : 0.f;                \
        float v2 = ok2 ? fmaxf(ACC[2] + bb + ws2 * wb, 0.f) : 0.f;                \
        float v3 = ok3 ? fmaxf(ACC[3] + bb + ws3 * wb, 0.f) : 0.f;                \
        if (ok0) A.out[(size_t)(orow + 0) * 64 + c] = f2b(v0);                    \
        if (ok1) A.out[(size_t)(orow + 1) * 64 + c] = f2b(v1);                    \
        if (ok2) A.out[(size_t)(orow + 2) * 64 + c] = f2b(v2);                    \
        if (ok3) A.out[(size_t)(orow + 3) * 64 + c] = f2b(v3);                    \
        if (A.statacc) {                                                          \
            float sv = (v0 + v1) + (v2 + v3);                                     \
            float qv = fmaf(v0, v0, fmaf(v1, v1, fmaf(v2, v2, v3 * v3)));         \
            sv += __shfl_xor(sv, 16); sv += __shfl_xor(sv, 32);                   \
            qv += __shfl_xor(qv, 16); qv += __shfl_xor(qv, 32);                   \
            if (lkg == 0) { lstat[wv][0][c] = sv; lstat[wv][1][c] = qv; }         \
        }                                                                         \
    }
    EPI(acc0, 0)
    EPI(acc1, 1)
    EPI(acc2, 2)
    EPI(acc3, 3)
#undef EPI
    if (A.statacc) {
        __syncthreads();
        if (t < 128) {
            int c = t & 63, p = t >> 6;
            atomicAdd(&A.statacc[p * 64 + c],
                      lstat[0][p][c] + lstat[1][p][c] + lstat[2][p][c] + lstat[3][p][c]);
        }
    }
}

// MERGED v+c layer: blocks [0,nbv) run v (NB2=1, 8-edge fast path), rest c (NB2=2).
__global__ __launch_bounds__(256, 4) void k_layer2(LArgs V, LArgs C,
                                                   const int2* __restrict__ erec, int nbv) {
    __shared__ __align__(16) u16 lagg[4][16][72];
    __shared__ float lstat[4][2][64];
    if ((int)blockIdx.x < nbv) layer_body<1>(V, erec, blockIdx.x, lagg, lstat);
    else                       layer_body<2>(C, erec, blockIdx.x - nbv, lagg, lstat);
}

// ---------------- pooling (merged v+c, counts fused) ----------------
static __device__ __forceinline__ void pool_body(const u16* __restrict__ x, const int* __restrict__ batch,
                                                 int n, float* __restrict__ sums, int* __restrict__ cnt,
                                                 int blk) {
    int c = threadIdx.x & 63, r4 = threadIdx.x >> 6;
    int base = blk * 128 + r4 * 32;
    int end = min(n, base + 32);
    float acc = 0.f; int curb = -1, runlen = 0;
    for (int i = base; i < end; ++i) {
        int b = batch[i];
        if (b != curb) {
            if (curb >= 0) {
                atomicAdd(&sums[curb * 64 + c], acc);
                if (c == 0) atomicAdd(&cnt[curb], runlen);
            }
            acc = 0.f; curb = b; runlen = 0;
        }
        acc += b2f(x[(size_t)i * 64 + c]);
        runlen++;
    }
    if (curb >= 0) {
        atomicAdd(&sums[curb * 64 + c], acc);
        if (c == 0) atomicAdd(&cnt[curb], runlen);
    }
}

__global__ __launch_bounds__(256) void k_pool2(const u16* __restrict__ xv, const u16* __restrict__ xc,
                           const int* __restrict__ bv, const int* __restrict__ bc,
                           float* __restrict__ sv, float* __restrict__ sc,
                           int* __restrict__ cv, int* __restrict__ cc, int nbv) {
    if ((int)blockIdx.x < nbv) pool_body(xv, bv, NVn, sv, cv, blockIdx.x);
    else                       pool_body(xc, bc, NCn, sc, cc, blockIdx.x - nbv);
}

__global__ __launch_bounds__(256) void k_pool_div(const float* __restrict__ sv, const float* __restrict__ sc,
                           const int* __restrict__ cv, const int* __restrict__ cc2,
                           float* __restrict__ out) {
    int idx = blockIdx.x * blockDim.x + threadIdx.x;
    if (idx >= NBb * 128) return;
    int b = idx >> 7, j = idx & 127;
    float v;
    if (j < 64) v = sv[b * 64 + j] / fmaxf((float)cv[b], 1.0f);
    else        v = sc[b * 64 + (j - 64)] / fmaxf((float)cc2[b], 1.0f);
    out[idx] = v;
}

// ==================================================================
extern "C" void kernel_launch(void* const* d_in, const int* in_sizes, int n_in,
                              void* d_out, int out_size, void* d_ws, size_t ws_size,
                              hipStream_t stream) {
    (void)in_sizes; (void)n_in; (void)out_size; (void)ws_size;
    const float* var_feats = (const float*)d_in[0];
    const float* cstr_feats = (const float*)d_in[1];
    const float* edge_attr = (const float*)d_in[2];
    const float* Wrel_v0 = (const float*)d_in[3];
    const float* brel_v0 = (const float*)d_in[4];
    const float* Wroot_v0 = (const float*)d_in[5];
    const float* Wrel_c0 = (const float*)d_in[6];
    const float* brel_c0 = (const float*)d_in[7];
    const float* Wroot_c0 = (const float*)d_in[8];
    const float* g_v0 = (const float*)d_in[9];
    const float* b_v0 = (const float*)d_in[10];
    const float* g_c0 = (const float*)d_in[11];
    const float* b_c0 = (const float*)d_in[12];
    const float* Wrel_v = (const float*)d_in[13];
    const float* brel_v = (const float*)d_in[14];
    const float* Wroot_v = (const float*)d_in[15];
    const float* Wrel_c = (const float*)d_in[16];
    const float* brel_c = (const float*)d_in[17];
    const float* Wroot_c = (const float*)d_in[18];
    const float* g_v = (const float*)d_in[19];
    const float* b_v = (const float*)d_in[20];
    const float* g_c = (const float*)d_in[21];
    const float* b_c = (const float*)d_in[22];
    const int* edge_index = (const int*)d_in[23];
    const int* var_batch = (const int*)d_in[24];
    const int* cstr_batch = (const int*)d_in[25];
    const int* src_c = edge_index;
    const int* dst_v = edge_index + NEn;
    float* out = (float*)d_out;

    // ---- workspace carve-out ----
    char* ws = (char*)d_ws;
    size_t off_b = 0;
    auto alloc = [&](size_t bytes) -> char* {
        char* p = ws + off_b;
        off_b = (off_b + bytes + 255) & ~(size_t)255;
        return p;
    };
    // bf16 feature ping-pong buffers
    u16* Vb[2] = { (u16*)alloc((size_t)NVn * 64 * 2), (u16*)alloc((size_t)NVn * 64 * 2) };
    u16* Cb[2] = { (u16*)alloc((size_t)NCn * 64 * 2), (u16*)alloc((size_t)NCn * 64 * 2) };
    // unified CSR: v rows [0,NVn), c rows [NVn,NVn+NCn); erec = 2M interleaved records
    constexpr int NT = NVn + NCn;
    int* off_all = (int*)alloc((size_t)(NT + 1) * 4);
    int* cur_all = (int*)alloc((size_t)NT * 4);
    int2* erec = (int2*)alloc((size_t)(2 * NEn) * 8);
    float* wsum_all = (float*)alloc((size_t)NT * 4);
    int* degzone = (int*)alloc((size_t)NT * 4);
    int* degv = degzone;
    int* degc = degzone + NVn;
    int* bsum = (int*)alloc(1024 * 4);
    // zero-init zone (one memset): stats accums + pool sums + counts
    float* zzone = (float*)alloc(4992 * 4);
    float* accL0v = zzone;            // 32 (18 used)
    float* accL0c = zzone + 32;       // 8 (2 used)
    float* accLv[3], *accLc[3];
    for (int l = 0; l < 3; l++) { accLv[l] = zzone + 64 + l * 256; accLc[l] = zzone + 64 + l * 256 + 128; }
    float* pool_sv = zzone + 832;     // 2048
    float* pool_sc = zzone + 2880;    // 2048
    int* cnt_v = (int*)(zzone + 4928);  // 32
    int* cnt_c = (int*)(zzone + 4960);  // 32
    // folded weights
    float* Wr_v = (float*)alloc(4096 * 4);
    float* Wt_v = (float*)alloc(4096 * 4);
    float* b0_v = (float*)alloc(64 * 4);
    float* bw_v = (float*)alloc(64 * 4);
    float* Wr_c = (float*)alloc(4096 * 4);
    float* Wt_c = (float*)alloc(4096 * 4);
    float* b0_c = (float*)alloc(64 * 4);
    float* bw_c = (float*)alloc(64 * 4);
    // bf16 MFMA B-fragment buffers: [ks4][ct4][lane64][8 bf16]
    u16* Bf_v = (u16*)alloc(8192 * 2);
    u16* Bf_c = (u16*)alloc(8192 * 2);

    const float invNV = 1.0f / (float)NVn;
    const float invNC = 1.0f / (float)NCn;
    const int* off_v = off_all;
    const int* off_c = off_all + NVn;
    float* wsum_v = wsum_all;
    float* wsum_c = wsum_all + NVn;

    // ---- init ----
    hipMemsetAsync(degzone, 0, (size_t)NT * 4, stream);
    hipMemsetAsync(zzone, 0, 4992 * 4, stream);

    // ---- build unified CSR (one scan + one fill for both directions) ----
    k_count_deg<<<1024, 256, 0, stream>>>(src_c, dst_v, degv, degc);
    int nbt = (NT + 1023) / 1024;  // 293
    k_scan_block<<<nbt, 256, 0, stream>>>(degzone, NT, bsum);
    k_scan_tops<<<1, 1024, 0, stream>>>(bsum, nbt);
    k_scan_final<<<nbt, 256, 0, stream>>>(degzone, NT, bsum, off_all, cur_all);
    k_fill_both<<<2048, 256, 0, stream>>>(src_c, dst_v, edge_attr, off_all, cur_all, erec);
    k_wsum_rec<<<(NT + 255) / 256, 256, 0, stream>>>(off_all, erec, wsum_all, NT);

    // ---- layer 0 (var: 9 feats, cstr: 1 feat) ----
    k_stats_small<9><<<784, 256, 0, stream>>>(var_feats, NVn, accL0v);
    k_stats_small<1><<<392, 256, 0, stream>>>(cstr_feats, NCn, accL0c);
    {
        FoldArgs fv = { Wrel_v0, brel_v0, Wroot_v0, g_c0, b_c0, accL0c, g_v0, b_v0, accL0v,
                        invNC, invNV, 1, 9, Wr_v, Wt_v, b0_v, bw_v, (u16*)nullptr };
        FoldArgs fc = { Wrel_c0, brel_c0, Wroot_c0, g_v0, b_v0, accL0v, g_c0, b_c0, accL0c,
                        invNV, invNC, 9, 1, Wr_c, Wt_c, b0_c, bw_c, (u16*)nullptr };
        k_fold2<<<2, 256, 0, stream>>>(fv, fc);
    }
    k_layer0<<<784 + 392, 256, 0, stream>>>(cstr_feats, var_feats, off_v, off_c, erec,
                                            wsum_v, wsum_c,
                                            Wr_v, Wt_v, b0_v, bw_v,
                                            Wr_c, Wt_c, b0_c, bw_c,
                                            Vb[0], Cb[0], accLv[0], accLc[0], 784);

    // ---- layers 1..3 (merged v+c fused layer) ----
    int nbv_l = (NVn + 63) / 64;   // 3125
    int nbc_l = (NCn + 63) / 64;   // 1563
    int cur = 0;
    for (int l = 0; l < 3; l++) {
        const float* Wrv = Wrel_v + (size_t)l * 4096;
        const float* brv = brel_v + (size_t)l * 64;
        const float* Wtv = Wroot_v + (size_t)l * 4096;
        const float* Wrc = Wrel_c + (size_t)l * 4096;
        const float* brc = brel_c + (size_t)l * 64;
        const float* Wtc = Wroot_c + (size_t)l * 4096;
        const float* gvl = g_v + (size_t)l * 64; const float* bvl = b_v + (size_t)l * 64;
        const float* gcl = g_c + (size_t)l * 64; const float* bcl = b_c + (size_t)l * 64;

        FoldArgs fv = { Wrv, brv, Wtv, gcl, bcl, accLc[l], gvl, bvl, accLv[l],
                        invNC, invNV, 64, 64, Wr_v, Wt_v, b0_v, bw_v, Bf_v };
        FoldArgs fc = { Wrc, brc, Wtc, gvl, bvl, accLv[l], gcl, bcl, accLc[l],
                        invNV, invNC, 64, 64, Wr_c, Wt_c, b0_c, bw_c, Bf_c };
        k_fold2<<<2, 256, 0, stream>>>(fv, fc);

        int nxt = cur ^ 1;
        float* sv = (l < 2) ? accLv[l + 1] : (float*)nullptr;
        float* sc = (l < 2) ? accLc[l + 1] : (float*)nullptr;
        LArgs LV = { Cb[cur], Vb[cur], off_v, wsum_v, Bf_v, b0_v, bw_v, Vb[nxt], sv, NVn };
        LArgs LC = { Vb[cur], Cb[cur], off_c, wsum_c, Bf_c, b0_c, bw_c, Cb[nxt], sc, NCn };
        k_layer2<<<nbv_l + nbc_l, 256, 0, stream>>>(LV, LC, erec, nbv_l);
        cur = nxt;
    }

    // ---- pooling (merged) ----
    int nbv_p = (NVn + 127) / 128;  // 1563
    int nbc_p = (NCn + 127) / 128;  // 782
    k_pool2<<<nbv_p + nbc_p, 256, 0, stream>>>(Vb[cur], Cb[cur], var_batch, cstr_batch,
                                               pool_sv, pool_sc, cnt_v, cnt_c, nbv_p);
    k_pool_div<<<(NBb * 128 + 255) / 256, 256, 0, stream>>>(pool_sv, pool_sc, cnt_v, cnt_c, out);
}

// Round 25
// 755.039 us; speedup vs baseline: 1.0288x; 1.0288x over previous
//
#include <hip/hip_runtime.h>

// Problem constants (match reference setup_inputs)
constexpr int NVn = 200000;   // var nodes, 9 feats in
constexpr int NCn = 100000;   // cstr nodes, 1 feat in
constexpr int NEn = 1000000;  // edges
constexpr int NBb = 32;       // graphs
#define EPSf 1e-5f

typedef unsigned short u16;
typedef __attribute__((ext_vector_type(8))) short s8v;   // 8 bf16 (4 VGPRs)
typedef __attribute__((ext_vector_type(4))) float f4v;   // 4 f32 acc

// f32 -> bf16 bits, round-to-nearest-even
static __device__ __forceinline__ u16 f2b(float f) {
    union { float f; unsigned u; } x; x.f = f;
    return (u16)((x.u + 0x7FFFu + ((x.u >> 16) & 1u)) >> 16);
}
static __device__ __forceinline__ float b2f(u16 u) {
    union { unsigned u; float f; } x; x.u = ((unsigned)u) << 16; return x.f;
}

// store folded weight W[kg][h] (kg in 0..127, h in 0..63) into MFMA B-fragment order:
// fragment (ks=kg>>5, ct=h>>4), lane = ((kg>>3)&3)<<4 | (h&15), elem j = kg&7
static __device__ __forceinline__ void frag_store(u16* B, int kg, int h, float w) {
    int ks = kg >> 5, g = (kg >> 3) & 3, j = kg & 7, ct = h >> 4;
    int lane = (g << 4) | (h & 15);
    B[((((ks << 2) | ct) << 6) | lane) * 8 + j] = f2b(w);
}

// ---------------- degree count (2 edges/thread, int2 loads) ----------------
__global__ __launch_bounds__(256) void k_count_deg(const int* __restrict__ src, const int* __restrict__ dst,
                            int* __restrict__ degv, int* __restrict__ degc) {
    int i = blockIdx.x * blockDim.x + threadIdx.x;
    for (int e2 = i; e2 < NEn / 2; e2 += gridDim.x * blockDim.x) {
        int2 s = ((const int2*)src)[e2];
        int2 d = ((const int2*)dst)[e2];
        atomicAdd(&degv[d.x], 1);
        atomicAdd(&degv[d.y], 1);
        atomicAdd(&degc[s.x], 1);
        atomicAdd(&degc[s.y], 1);
    }
}

// ---------------- exclusive scan (3 kernels, 1024 elems/block) ----------------
__global__ __launch_bounds__(256) void k_scan_block(const int* __restrict__ deg, int n, int* __restrict__ bsum) {
    __shared__ int s[256];
    int base = blockIdx.x * 1024;
    int t = threadIdx.x;
    int v = 0;
#pragma unroll
    for (int j = 0; j < 4; j++) { int idx = base + t * 4 + j; if (idx < n) v += deg[idx]; }
    s[t] = v; __syncthreads();
    for (int o = 128; o > 0; o >>= 1) { if (t < o) s[t] += s[t + o]; __syncthreads(); }
    if (t == 0) bsum[blockIdx.x] = s[0];
}

__global__ __launch_bounds__(1024) void k_scan_tops(int* bsum, int nb) {
    __shared__ int s[1024];
    int t = threadIdx.x;
    int v = (t < nb) ? bsum[t] : 0;
    s[t] = v; __syncthreads();
    for (int o = 1; o < 1024; o <<= 1) {
        int x = (t >= o) ? s[t - o] : 0; __syncthreads();
        s[t] += x; __syncthreads();
    }
    if (t < nb) bsum[t] = s[t] - v;  // exclusive
}

__global__ __launch_bounds__(256) void k_scan_final(const int* __restrict__ deg, int n, const int* __restrict__ bsum,
                             int* __restrict__ off, int* __restrict__ cur) {
    __shared__ int s[256];
    int base = blockIdx.x * 1024, t = threadIdx.x;
    int d[4], loc[4], sum = 0;
#pragma unroll
    for (int j = 0; j < 4; j++) {
        int idx = base + t * 4 + j;
        d[j] = (idx < n) ? deg[idx] : 0;
        loc[j] = sum; sum += d[j];
    }
    s[t] = sum; __syncthreads();
    int v = sum;
    for (int o = 1; o < 256; o <<= 1) {
        int x = (t >= o) ? s[t - o] : 0; __syncthreads();
        s[t] += x; __syncthreads();
    }
    int texcl = s[t] - v + bsum[blockIdx.x];
#pragma unroll
    for (int j = 0; j < 4; j++) {
        int idx = base + t * 4 + j;
        if (idx < n) {
            int o2 = texcl + loc[j];
            off[idx] = o2; cur[idx] = o2;
            if (idx == n - 1) off[n] = o2 + d[j];
        }
    }
}

// ---------------- CSR fill, BOTH directions in one pass ----------------
__global__ __launch_bounds__(256) void k_fill_both(const int* __restrict__ src, const int* __restrict__ dst,
                       const float* __restrict__ ew, const int* __restrict__ off,
                       int* __restrict__ cur, int2* __restrict__ erec) {
    for (int e = blockIdx.x * blockDim.x + threadIdx.x; e < NEn; e += gridDim.x * blockDim.x) {
        int s = src[e], d = dst[e];
        float a = ew[e];
        int degv = off[d + 1] - off[d];
        int p = atomicAdd(&cur[d], 1);
        erec[p] = make_int2(s, __float_as_int(a * (1.0f / (float)degv)));
        int kc = NVn + s;
        int degc = off[kc + 1] - off[kc];
        int p2 = atomicAdd(&cur[kc], 1);
        erec[p2] = make_int2(d, __float_as_int(a * (1.0f / (float)degc)));
    }
}

// wsum[i] = sum of (ew/deg) over row
__global__ __launch_bounds__(256) void k_wsum_rec(const int* __restrict__ off, const int2* __restrict__ erec,
                       float* __restrict__ ws, int n) {
    for (int i = blockIdx.x * blockDim.x + threadIdx.x; i < n; i += gridDim.x * blockDim.x) {
        int s = off[i], e = off[i + 1]; float t = 0.f;
        for (int j = s; j < e; j++) t += __int_as_float(erec[j].y);
        ws[i] = t;
    }
}

// f32 input, small D: 1 row/thread, wave shuffle-reduce, 2D atomics/block
template <int D>
__global__ __launch_bounds__(256) void k_stats_small(const float* __restrict__ x, int n, float* __restrict__ acc) {
    float s[D], q[D];
#pragma unroll
    for (int k = 0; k < D; k++) { s[k] = 0.f; q[k] = 0.f; }
    for (int i = blockIdx.x * blockDim.x + threadIdx.x; i < n; i += gridDim.x * blockDim.x) {
#pragma unroll
        for (int k = 0; k < D; k++) { float v = x[(size_t)i * D + k]; s[k] += v; q[k] = fmaf(v, v, q[k]); }
    }
#pragma unroll
    for (int k = 0; k < D; k++) {
#pragma unroll
        for (int o = 32; o > 0; o >>= 1) {
            s[k] += __shfl_down(s[k], o);
            q[k] += __shfl_down(q[k], o);
        }
    }
    __shared__ float ls[4][2 * D];
    int lane = threadIdx.x & 63, wv = threadIdx.x >> 6;
    if (lane == 0) {
#pragma unroll
        for (int k = 0; k < D; k++) { ls[wv][k] = s[k]; ls[wv][D + k] = q[k]; }
    }
    __syncthreads();
    int t = threadIdx.x;
    if (t < 2 * D) atomicAdd(&acc[t], ls[0][t] + ls[1][t] + ls[2][t] + ls[3][t]);
}

// ---------------- fold BN into weights (2 param sets in one launch; block 0=A, 1=B) ------
struct FoldArgs {
    const float *Wrel, *brel, *Wroot, *gs, *bs, *accs, *gd, *bd, *accd;
    float invNs, invNd;
    int DSv, DDv;
    float *Wr_o, *Wt_o, *b0_o, *bw_o;
    u16* Bfrag;
};

__global__ __launch_bounds__(256) void k_fold2(FoldArgs A, FoldArgs B) {
    const FoldArgs F = blockIdx.x ? B : A;
    __shared__ float sa[128], sbe[128];
    __shared__ float rb0[4][64], rbw[4][64];
    int t = threadIdx.x;
    int total = F.DSv + F.DDv;
    for (int k = t; k < total; k += 256) {
        bool isrc = k < F.DSv;
        int kk = isrc ? k : k - F.DSv;
        const float* acc = isrc ? F.accs : F.accd;
        float invN = isrc ? F.invNs : F.invNd;
        int D = isrc ? F.DSv : F.DDv;
        float g = isrc ? F.gs[kk] : F.gd[kk];
        float b = isrc ? F.bs[kk] : F.bd[kk];
        float m = acc[kk] * invN;
        float var = acc[D + kk] * invN - m * m;
        float a = g * rsqrtf(var + EPSf);
        sa[k] = a; sbe[k] = b - m * a;
    }
    __syncthreads();
    int h = t & 63, q = t >> 6;
    float bw = 0.f, b0 = 0.f;
    for (int k = q; k < F.DSv; k += 4) {
        float wv = F.Wrel[k * 64 + h];
        float wf = sa[k] * wv;
        F.Wr_o[k * 64 + h] = wf;
        bw = fmaf(sbe[k], wv, bw);
        if (F.Bfrag) frag_store(F.Bfrag, k, h, wf);
    }
    for (int k = q; k < F.DDv; k += 4) {
        float wv = F.Wroot[k * 64 + h];
        float wf = sa[F.DSv + k] * wv;
        F.Wt_o[k * 64 + h] = wf;
        b0 = fmaf(sbe[F.DSv + k], wv, b0);
        if (F.Bfrag) frag_store(F.Bfrag, 64 + k, h, wf);
    }
    rb0[q][h] = b0; rbw[q][h] = bw;
    __syncthreads();
    if (q == 0) {
        F.b0_o[h] = F.brel[h] + rb0[0][h] + rb0[1][h] + rb0[2][h] + rb0[3][h];
        F.bw_o[h] = rbw[0][h] + rbw[1][h] + rbw[2][h] + rbw[3][h];
    }
}

// ---------------- MERGED layer 0 (v blocks then c blocks) --------
__global__ __launch_bounds__(256, 4) void k_layer0(
        const float* __restrict__ cf, const float* __restrict__ vf,
        const int* __restrict__ off_v, const int* __restrict__ off_c,
        const int2* __restrict__ erec,
        const float* __restrict__ wsum_v, const float* __restrict__ wsum_c,
        const float* __restrict__ Wr_v, const float* __restrict__ Wt_v,
        const float* __restrict__ b0_v, const float* __restrict__ bw_v,
        const float* __restrict__ Wr_c, const float* __restrict__ Wt_c,
        const float* __restrict__ b0_c, const float* __restrict__ bw_c,
        u16* __restrict__ outv, u16* __restrict__ outc,
        float* __restrict__ accv, float* __restrict__ accc, int nbv) {
    __shared__ float ls[4][128];
    int t = threadIdx.x, h = t & 63, wv = t >> 6;
    if ((int)blockIdx.x < nbv) {
        // ---- v-update: 4 rows/wave; 16-lane gather groups ----
        int wid = blockIdx.x * 4 + wv, nw = nbv * 4;
        int grp = h >> 4, sub = h & 15;
        float wr = Wr_v[h], bb = b0_v[h], wb = bw_v[h];
        float wt[9];
#pragma unroll
        for (int k = 0; k < 9; k++) wt[k] = Wt_v[k * 64 + h];
        float ssum = 0.f, sq = 0.f;
        for (int i0 = wid * 4; i0 < NVn; i0 += nw * 4) {
            int row = i0 + grp;
            bool ok = row < NVn;
            int s = ok ? off_v[row] : 0;
            int e = ok ? off_v[row + 1] : 0;
            float p = 0.f;
            for (int j = s + sub; j < e; j += 16) {
                int2 r = erec[j];
                p = fmaf(__int_as_float(r.y), cf[r.x], p);
            }
            p += __shfl_xor(p, 1); p += __shfl_xor(p, 2);
            p += __shfl_xor(p, 4); p += __shfl_xor(p, 8);
#pragma unroll
            for (int r = 0; r < 4; ++r) {
                int orow = i0 + r;
                if (orow >= NVn) break;
                float pr = __shfl(p, r * 16);
                float acc = fmaf(pr, wr, bb) + wsum_v[orow] * wb;
#pragma unroll
                for (int k = 0; k < 9; k++) acc = fmaf(vf[(size_t)orow * 9 + k], wt[k], acc);
                float v = fmaxf(acc, 0.f);
                outv[(size_t)orow * 64 + h] = f2b(v);
                ssum += v; sq = fmaf(v, v, sq);
            }
        }
        ls[wv][h] = ssum; ls[wv][64 + h] = sq;
        __syncthreads();
        if (t < 128) atomicAdd(&accv[t], ls[0][t] + ls[1][t] + ls[2][t] + ls[3][t]);
    } else {
        // ---- c-update: 2 rows/wave; 32-lane gather groups (9 feats) ----
        int blk = blockIdx.x - nbv;
        int nbc = gridDim.x - nbv;
        int wid = blk * 4 + wv, nw = nbc * 4;
        int grp = h >> 5, sub = h & 31;
        float wtt = Wt_c[h], bb = b0_c[h], wb = bw_c[h];
        float wr[9];
#pragma unroll
        for (int k = 0; k < 9; k++) wr[k] = Wr_c[k * 64 + h];
        float ssum = 0.f, sq = 0.f;
        for (int i0 = wid * 2; i0 < NCn; i0 += nw * 2) {
            int row = i0 + grp;
            bool ok = row < NCn;
            int s = ok ? off_c[row] : 0;
            int e = ok ? off_c[row + 1] : 0;
            float p[9];
#pragma unroll
            for (int k = 0; k < 9; k++) p[k] = 0.f;
            for (int j = s + sub; j < e; j += 32) {
                int2 r = erec[j];
                float w = __int_as_float(r.y);
#pragma unroll
                for (int k = 0; k < 9; k++) p[k] = fmaf(w, vf[(size_t)r.x * 9 + k], p[k]);
            }
#pragma unroll
            for (int k = 0; k < 9; k++) {
                p[k] += __shfl_xor(p[k], 1); p[k] += __shfl_xor(p[k], 2);
                p[k] += __shfl_xor(p[k], 4); p[k] += __shfl_xor(p[k], 8);
                p[k] += __shfl_xor(p[k], 16);
            }
#pragma unroll
            for (int r = 0; r < 2; ++r) {
                int orow = i0 + r;
                if (orow >= NCn) break;
                float acc = fmaf(cf[orow], wtt, bb) + wsum_c[orow] * wb;
#pragma unroll
                for (int k = 0; k < 9; k++) {
                    float pr = __shfl(p[k], r * 32);
                    acc = fmaf(pr, wr[k], acc);
                }
                float v = fmaxf(acc, 0.f);
                outc[(size_t)orow * 64 + h] = f2b(v);
                ssum += v; sq = fmaf(v, v, sq);
            }
        }
        ls[wv][h] = ssum; ls[wv][64 + h] = sq;
        __syncthreads();
        if (t < 128) atomicAdd(&accc[t], ls[0][t] + ls[1][t] + ls[2][t] + ls[3][t]);
    }
}

// ---------------- FUSED layer body: agg (gather) + MFMA GEMM + epilogue + stats ----
struct LArgs {
    const u16 *xs, *xr;
    const int* off;
    const float* wsum;
    const u16* Bfrag;
    const float *b0v, *bwv;
    u16* out;
    float* statacc;
    int n;
};

template <int NB>
static __device__ __forceinline__ void layer_body(const LArgs& A, const int2* __restrict__ erec,
                                                  int blk, u16 (*lagg)[16][72], float (*lstat)[2][64]) {
    constexpr int RPB = 16 / NB;   // rows per batch
    int t = threadIdx.x;
    int wv = t >> 6, l = t & 63;
    int lrow = l & 15, lkg = l >> 4;
    int base = blk * 64 + wv * 16;
    int n = A.n;
    // phase 1: aggregate
    {
        int g = l >> 4, qi = l & 15;
        int offv = 0;
        if (l < 17) { int idx = base + l; offv = A.off[idx > n ? n : idx]; }
#pragma unroll
        for (int ob = 0; ob < NB; ++ob) {
            int s_[RPB], e_[RPB];
            int cc[RPB][NB];
            float ww[RPB][NB];
#pragma unroll
            for (int rr = 0; rr < RPB; ++rr) {
                int r = ob * RPB + rr;
                int s = __shfl(offv, r);
                int e = __shfl(offv, r + 1);
                s_[rr] = s; e_[rr] = e;
#pragma unroll
                for (int b = 0; b < NB; ++b) {
                    int d = e - s - 4 * b;
                    int idx = (d > 0) ? (s + 4 * b + (g < d ? g : 0)) : 0;
                    int2 rec = erec[idx];
                    cc[rr][b] = rec.x;
                    float wv2 = __int_as_float(rec.y);
                    if (g >= d) wv2 = 0.f;
                    ww[rr][b] = wv2;
                }
            }
            ushort4 ft[RPB][NB];
#pragma unroll
            for (int rr = 0; rr < RPB; ++rr)
#pragma unroll
                for (int b = 0; b < NB; ++b)
                    ft[rr][b] = *(const ushort4*)(A.xs + (size_t)cc[rr][b] * 64 + qi * 4);
#pragma unroll
            for (int rr = 0; rr < RPB; ++rr) {
                float a0 = 0.f, a1 = 0.f, a2 = 0.f, a3 = 0.f;
#pragma unroll
                for (int b = 0; b < NB; ++b) {
                    a0 = fmaf(ww[rr][b], b2f(ft[rr][b].x), a0);
                    a1 = fmaf(ww[rr][b], b2f(ft[rr][b].y), a1);
                    a2 = fmaf(ww[rr][b], b2f(ft[rr][b].z), a2);
                    a3 = fmaf(ww[rr][b], b2f(ft[rr][b].w), a3);
                }
                for (int j = s_[rr] + 4 * NB; j < e_[rr]; j += 4) {
                    int rem = e_[rr] - j;
                    int i2 = j + (g < rem ? g : 0);
                    int2 rec = erec[i2];
                    float w2 = __int_as_float(rec.y); if (g >= rem) w2 = 0.f;
                    ushort4 f2 = *(const ushort4*)(A.xs + (size_t)rec.x * 64 + qi * 4);
                    a0 = fmaf(w2, b2f(f2.x), a0);
                    a1 = fmaf(w2, b2f(f2.y), a1);
                    a2 = fmaf(w2, b2f(f2.z), a2);
                    a3 = fmaf(w2, b2f(f2.w), a3);
                }
                a0 += __shfl_xor(a0, 16); a0 += __shfl_xor(a0, 32);
                a1 += __shfl_xor(a1, 16); a1 += __shfl_xor(a1, 32);
                a2 += __shfl_xor(a2, 16); a2 += __shfl_xor(a2, 32);
                a3 += __shfl_xor(a3, 16); a3 += __shfl_xor(a3, 32);
                if (g == 0) {
                    ushort4 o;
                    o.x = f2b(a0); o.y = f2b(a1); o.z = f2b(a2); o.w = f2b(a3);
                    *(ushort4*)&lagg[wv][ob * RPB + rr][qi * 4] = o;
                }
            }
        }
    }
    // phase 2: MFMA (per-wave LDS region: wave-synchronous, no barrier needed)
    const u16* Bl = A.Bfrag + l * 8;
    f4v acc0 = {0.f, 0.f, 0.f, 0.f};
    f4v acc1 = acc0, acc2 = acc0, acc3 = acc0;
#define LSTEP(ks, APTR)                                                       \
    {                                                                         \
        s8v a = *(const s8v*)(APTR);                                          \
        s8v f0 = *(const s8v*)(Bl + ((ks) * 4 + 0) * 512);                    \
        s8v f1 = *(const s8v*)(Bl + ((ks) * 4 + 1) * 512);                    \
        s8v f2 = *(const s8v*)(Bl + ((ks) * 4 + 2) * 512);                    \
        s8v f3 = *(const s8v*)(Bl + ((ks) * 4 + 3) * 512);                    \
        acc0 = __builtin_amdgcn_mfma_f32_16x16x32_bf16(a, f0, acc0, 0, 0, 0); \
        acc1 = __builtin_amdgcn_mfma_f32_16x16x32_bf16(a, f1, acc1, 0, 0, 0); \
        acc2 = __builtin_amdgcn_mfma_f32_16x16x32_bf16(a, f2, acc2, 0, 0, 0); \
        acc3 = __builtin_amdgcn_mfma_f32_16x16x32_bf16(a, f3, acc3, 0, 0, 0); \
    }
    LSTEP(0, &lagg[wv][lrow][lkg * 8])
    LSTEP(1, &lagg[wv][lrow][32 + lkg * 8])
    int arow = base + lrow; if (arow >= n) arow = 0;
    const u16* xp = A.xr + (size_t)arow * 64 + lkg * 8;
    LSTEP(2, xp)
    LSTEP(3, xp + 32)
#undef LSTEP
    // phase 3: epilogue + stats
    int orow = base + lkg * 4;
    bool ok0 = orow + 0 < n, ok1 = orow + 1 < n, ok2 = orow + 2 < n, ok3 = orow + 3 < n;
    float ws0 = ok0 ? A.wsum[orow + 0] : 0.f;
    float ws1 = ok1 ? A.wsum[orow + 1] : 0.f;
    float ws2 = ok2 ? A.wsum[orow + 2] : 0.f;
    float ws3 = ok3 ? A.wsum[orow + 3] : 0.f;
#define EPI(ACC, ct)                                                              \
    {                                                                             \
        int c = (ct) * 16 + lrow;                                                 \
        float bb = A.b0v[c], wb = A.bwv[c];                                       \
        float v0 = ok0 ? fmaxf(ACC[0] + bb + ws0 * wb, 0.f) : 0.f;                \
        float v1 = ok1 ? fmaxf(ACC[1] + bb + ws1 * wb, 0.f) : 0.f;                \
        float v2 = ok2 ? fmaxf(ACC[2] + bb + ws2 * wb, 0.f) : 0.f;                \
        float v3 = ok3 ? fmaxf(ACC[3] + bb + ws3 * wb, 0.f) : 0.f;                \
        if (ok0) A.out[(size_t)(orow + 0) * 64 + c] = f2b(v0);                    \
        if (ok1) A.out[(size_t)(orow + 1) * 64 + c] = f2b(v1);                    \
        if (ok2) A.out[(size_t)(orow + 2) * 64 + c] = f2b(v2);                    \
        if (ok3) A.out[(size_t)(orow + 3) * 64 + c] = f2b(v3);                    \
        if (A.statacc) {                                                          \
            float sv = (v0 + v1) + (v2 + v3);                                     \
            float qv = fmaf(v0, v0, fmaf(v1, v1, fmaf(v2, v2, v3 * v3)));         \
            sv += __shfl_xor(sv, 16); sv += __shfl_xor(sv, 32);                   \
            qv += __shfl_xor(qv, 16); qv += __shfl_xor(qv, 32);                   \
            if (lkg == 0) { lstat[wv][0][c] = sv; lstat[wv][1][c] = qv; }         \
        }                                                                         \
    }
    EPI(acc0, 0)
    EPI(acc1, 1)
    EPI(acc2, 2)
    EPI(acc3, 3)
#undef EPI
    if (A.statacc) {
        __syncthreads();
        if (t < 128) {
            int c = t & 63, p = t >> 6;
            atomicAdd(&A.statacc[p * 64 + c],
                      lstat[0][p][c] + lstat[1][p][c] + lstat[2][p][c] + lstat[3][p][c]);
        }
    }
}

// MERGED v+c layer: blocks [0,nbv) run v (NB=2), rest run c (NB=4).
__global__ __launch_bounds__(256, 4) void k_layer2(LArgs V, LArgs C,
                                                   const int2* __restrict__ erec, int nbv) {
    __shared__ __align__(16) u16 lagg[4][16][72];
    __shared__ float lstat[4][2][64];
    if ((int)blockIdx.x < nbv) layer_body<2>(V, erec, blockIdx.x, lagg, lstat);
    else                       layer_body<4>(C, erec, blockIdx.x - nbv, lagg, lstat);
}

// ---------------- pooling (merged v+c, counts fused) ----------------
static __device__ __forceinline__ void pool_body(const u16* __restrict__ x, const int* __restrict__ batch,
                                                 int n, float* __restrict__ sums, int* __restrict__ cnt,
                                                 int blk) {
    int c = threadIdx.x & 63, r4 = threadIdx.x >> 6;
    int base = blk * 128 + r4 * 32;
    int end = min(n, base + 32);
    float acc = 0.f; int curb = -1, runlen = 0;
    for (int i = base; i < end; ++i) {
        int b = batch[i];
        if (b != curb) {
            if (curb >= 0) {
                atomicAdd(&sums[curb * 64 + c], acc);
                if (c == 0) atomicAdd(&cnt[curb], runlen);
            }
            acc = 0.f; curb = b; runlen = 0;
        }
        acc += b2f(x[(size_t)i * 64 + c]);
        runlen++;
    }
    if (curb >= 0) {
        atomicAdd(&sums[curb * 64 + c], acc);
        if (c == 0) atomicAdd(&cnt[curb], runlen);
    }
}

__global__ __launch_bounds__(256) void k_pool2(const u16* __restrict__ xv, const u16* __restrict__ xc,
                           const int* __restrict__ bv, const int* __restrict__ bc,
                           float* __restrict__ sv, float* __restrict__ sc,
                           int* __restrict__ cv, int* __restrict__ cc, int nbv) {
    if ((int)blockIdx.x < nbv) pool_body(xv, bv, NVn, sv, cv, blockIdx.x);
    else                       pool_body(xc, bc, NCn, sc, cc, blockIdx.x - nbv);
}

__global__ __launch_bounds__(256) void k_pool_div(const float* __restrict__ sv, const float* __restrict__ sc,
                           const int* __restrict__ cv, const int* __restrict__ cc2,
                           float* __restrict__ out) {
    int idx = blockIdx.x * blockDim.x + threadIdx.x;
    if (idx >= NBb * 128) return;
    int b = idx >> 7, j = idx & 127;
    float v;
    if (j < 64) v = sv[b * 64 + j] / fmaxf((float)cv[b], 1.0f);
    else        v = sc[b * 64 + (j - 64)] / fmaxf((float)cc2[b], 1.0f);
    out[idx] = v;
}

// ==================================================================
extern "C" void kernel_launch(void* const* d_in, const int* in_sizes, int n_in,
                              void* d_out, int out_size, void* d_ws, size_t ws_size,
                              hipStream_t stream) {
    (void)in_sizes; (void)n_in; (void)out_size; (void)ws_size;
    const float* var_feats = (const float*)d_in[0];
    const float* cstr_feats = (const float*)d_in[1];
    const float* edge_attr = (const float*)d_in[2];
    const float* Wrel_v0 = (const float*)d_in[3];
    const float* brel_v0 = (const float*)d_in[4];
    const float* Wroot_v0 = (const float*)d_in[5];
    const float* Wrel_c0 = (const float*)d_in[6];
    const float* brel_c0 = (const float*)d_in[7];
    const float* Wroot_c0 = (const float*)d_in[8];
    const float* g_v0 = (const float*)d_in[9];
    const float* b_v0 = (const float*)d_in[10];
    const float* g_c0 = (const float*)d_in[11];
    const float* b_c0 = (const float*)d_in[12];
    const float* Wrel_v = (const float*)d_in[13];
    const float* brel_v = (const float*)d_in[14];
    const float* Wroot_v = (const float*)d_in[15];
    const float* Wrel_c = (const float*)d_in[16];
    const float* brel_c = (const float*)d_in[17];
    const float* Wroot_c = (const float*)d_in[18];
    const float* g_v = (const float*)d_in[19];
    const float* b_v = (const float*)d_in[20];
    const float* g_c = (const float*)d_in[21];
    const float* b_c = (const float*)d_in[22];
    const int* edge_index = (const int*)d_in[23];
    const int* var_batch = (const int*)d_in[24];
    const int* cstr_batch = (const int*)d_in[25];
    const int* src_c = edge_index;
    const int* dst_v = edge_index + NEn;
    float* out = (float*)d_out;

    // ---- workspace carve-out ----
    char* ws = (char*)d_ws;
    size_t off_b = 0;
    auto alloc = [&](size_t bytes) -> char* {
        char* p = ws + off_b;
        off_b = (off_b + bytes + 255) & ~(size_t)255;
        return p;
    };
    // bf16 feature ping-pong buffers
    u16* Vb[2] = { (u16*)alloc((size_t)NVn * 64 * 2), (u16*)alloc((size_t)NVn * 64 * 2) };
    u16* Cb[2] = { (u16*)alloc((size_t)NCn * 64 * 2), (u16*)alloc((size_t)NCn * 64 * 2) };
    // unified CSR: v rows [0,NVn), c rows [NVn,NVn+NCn); erec = 2M interleaved records
    constexpr int NT = NVn + NCn;
    int* off_all = (int*)alloc((size_t)(NT + 1) * 4);
    int* cur_all = (int*)alloc((size_t)NT * 4);
    int2* erec = (int2*)alloc((size_t)(2 * NEn) * 8);
    float* wsum_all = (float*)alloc((size_t)NT * 4);
    int* degzone = (int*)alloc((size_t)NT * 4);
    int* degv = degzone;
    int* degc = degzone + NVn;
    int* bsum = (int*)alloc(1024 * 4);
    // zero-init zone (one memset): stats accums + pool sums + counts
    float* zzone = (float*)alloc(4992 * 4);
    float* accL0v = zzone;            // 32 (18 used)
    float* accL0c = zzone + 32;       // 8 (2 used)
    float* accLv[3], *accLc[3];
    for (int l = 0; l < 3; l++) { accLv[l] = zzone + 64 + l * 256; accLc[l] = zzone + 64 + l * 256 + 128; }
    float* pool_sv = zzone + 832;     // 2048
    float* pool_sc = zzone + 2880;    // 2048
    int* cnt_v = (int*)(zzone + 4928);  // 32
    int* cnt_c = (int*)(zzone + 4960);  // 32
    // folded weights
    float* Wr_v = (float*)alloc(4096 * 4);
    float* Wt_v = (float*)alloc(4096 * 4);
    float* b0_v = (float*)alloc(64 * 4);
    float* bw_v = (float*)alloc(64 * 4);
    float* Wr_c = (float*)alloc(4096 * 4);
    float* Wt_c = (float*)alloc(4096 * 4);
    float* b0_c = (float*)alloc(64 * 4);
    float* bw_c = (float*)alloc(64 * 4);
    // bf16 MFMA B-fragment buffers: [ks4][ct4][lane64][8 bf16]
    u16* Bf_v = (u16*)alloc(8192 * 2);
    u16* Bf_c = (u16*)alloc(8192 * 2);

    const float invNV = 1.0f / (float)NVn;
    const float invNC = 1.0f / (float)NCn;
    const int* off_v = off_all;
    const int* off_c = off_all + NVn;
    float* wsum_v = wsum_all;
    float* wsum_c = wsum_all + NVn;

    // ---- init ----
    hipMemsetAsync(degzone, 0, (size_t)NT * 4, stream);
    hipMemsetAsync(zzone, 0, 4992 * 4, stream);

    // ---- build unified CSR (one scan + one fill for both directions) ----
    k_count_deg<<<1024, 256, 0, stream>>>(src_c, dst_v, degv, degc);
    int nbt = (NT + 1023) / 1024;  // 293
    k_scan_block<<<nbt, 256, 0, stream>>>(degzone, NT, bsum);
    k_scan_tops<<<1, 1024, 0, stream>>>(bsum, nbt);
    k_scan_final<<<nbt, 256, 0, stream>>>(degzone, NT, bsum, off_all, cur_all);
    k_fill_both<<<2048, 256, 0, stream>>>(src_c, dst_v, edge_attr, off_all, cur_all, erec);
    k_wsum_rec<<<(NT + 255) / 256, 256, 0, stream>>>(off_all, erec, wsum_all, NT);

    // ---- layer 0 (var: 9 feats, cstr: 1 feat) ----
    k_stats_small<9><<<784, 256, 0, stream>>>(var_feats, NVn, accL0v);
    k_stats_small<1><<<392, 256, 0, stream>>>(cstr_feats, NCn, accL0c);
    {
        FoldArgs fv = { Wrel_v0, brel_v0, Wroot_v0, g_c0, b_c0, accL0c, g_v0, b_v0, accL0v,
                        invNC, invNV, 1, 9, Wr_v, Wt_v, b0_v, bw_v, (u16*)nullptr };
        FoldArgs fc = { Wrel_c0, brel_c0, Wroot_c0, g_v0, b_v0, accL0v, g_c0, b_c0, accL0c,
                        invNV, invNC, 9, 1, Wr_c, Wt_c, b0_c, bw_c, (u16*)nullptr };
        k_fold2<<<2, 256, 0, stream>>>(fv, fc);
    }
    k_layer0<<<784 + 392, 256, 0, stream>>>(cstr_feats, var_feats, off_v, off_c, erec,
                                            wsum_v, wsum_c,
                                            Wr_v, Wt_v, b0_v, bw_v,
                                            Wr_c, Wt_c, b0_c, bw_c,
                                            Vb[0], Cb[0], accLv[0], accLc[0], 784);

    // ---- layers 1..3 (merged v+c fused layer) ----
    int nbv_l = (NVn + 63) / 64;   // 3125
    int nbc_l = (NCn + 63) / 64;   // 1563
    int cur = 0;
    for (int l = 0; l < 3; l++) {
        const float* Wrv = Wrel_v + (size_t)l * 4096;
        const float* brv = brel_v + (size_t)l * 64;
        const float* Wtv = Wroot_v + (size_t)l * 4096;
        const float* Wrc = Wrel_c + (size_t)l * 4096;
        const float* brc = brel_c + (size_t)l * 64;
        const float* Wtc = Wroot_c + (size_t)l * 4096;
        const float* gvl = g_v + (size_t)l * 64; const float* bvl = b_v + (size_t)l * 64;
        const float* gcl = g_c + (size_t)l * 64; const float* bcl = b_c + (size_t)l * 64;

        FoldArgs fv = { Wrv, brv, Wtv, gcl, bcl, accLc[l], gvl, bvl, accLv[l],
                        invNC, invNV, 64, 64, Wr_v, Wt_v, b0_v, bw_v, Bf_v };
        FoldArgs fc = { Wrc, brc, Wtc, gvl, bvl, accLv[l], gcl, bcl, accLc[l],
                        invNV, invNC, 64, 64, Wr_c, Wt_c, b0_c, bw_c, Bf_c };
        k_fold2<<<2, 256, 0, stream>>>(fv, fc);

        int nxt = cur ^ 1;
        float* sv = (l < 2) ? accLv[l + 1] : (float*)nullptr;
        float* sc = (l < 2) ? accLc[l + 1] : (float*)nullptr;
        LArgs LV = { Cb[cur], Vb[cur], off_v, wsum_v, Bf_v, b0_v, bw_v, Vb[nxt], sv, NVn };
        LArgs LC = { Vb[cur], Cb[cur], off_c, wsum_c, Bf_c, b0_c, bw_c, Cb[nxt], sc, NCn };
        k_layer2<<<nbv_l + nbc_l, 256, 0, stream>>>(LV, LC, erec, nbv_l);
        cur = nxt;
    }

    // ---- pooling (merged) ----
    int nbv_p = (NVn + 127) / 128;  // 1563
    int nbc_p = (NCn + 127) / 128;  // 782
    k_pool2<<<nbv_p + nbc_p, 256, 0, stream>>>(Vb[cur], Cb[cur], var_batch, cstr_batch,
                                               pool_sv, pool_sc, cnt_v, cnt_c, nbv_p);
    k_pool_div<<<(NBb * 128 + 255) / 256, 256, 0, stream>>>(pool_sv, pool_sc, cnt_v, cnt_c, out);
}